// Round 7
// baseline (3989.561 us; speedup 1.0000x reference)
//
#include <hip/hip_runtime.h>

typedef unsigned short ushort_t;
typedef __bf16 bf16x8 __attribute__((ext_vector_type(8)));
typedef float f32x4 __attribute__((ext_vector_type(4)));

#define PACK_W_ELEMS (16*9*4*512)          // 294912 bf16 per LSTM: [wp16=wv*2+p][kt9][g4][512]
#define HEAD_ELEMS   (9*512)               // 1 n-tile x 9 k-tiles
#define PACK_TOTAL   (4*PACK_W_ELEMS + 2*HEAD_ELEMS)
#define FLAG_OFS     PACK_TOTAL            // ushort index of int dtype flag

__device__ __forceinline__ float bf2f(ushort_t u){ return __uint_as_float(((unsigned)u)<<16); }
__device__ __forceinline__ ushort_t f2bf(float f){
  __bf16 h = (__bf16)f;                    // HW RTNE convert (values bounded)
  return *(ushort_t*)&h;
}
__device__ __forceinline__ float rcp_(float x){ return __builtin_amdgcn_rcpf(x); }
__device__ __forceinline__ float sigmf_(float x){ return rcp_(1.0f + __expf(-x)); }
__device__ __forceinline__ float tanhf_(float x){ return 1.0f - 2.0f*rcp_(1.0f + __expf(2.0f*x)); }

__device__ __forceinline__ int sniff_f32(const ushort_t* w){
  int f32 = 0;
  #pragma unroll
  for (int i = 0; i < 32; ++i){
    float f = bf2f(w[2*i]);
    if (!(f > -8.f && f < 8.f)) f32 = 1;
  }
  return f32;
}
__device__ __forceinline__ float ldin(const ushort_t* p, int i, int f32){
  return f32 ? ((const float*)p)[i] : bf2f(p[i]);
}
__device__ __forceinline__ ushort_t ldw(const ushort_t* p, int i, int f32){
  return f32 ? f2bf(((const float*)p)[i]) : p[i];
}

// ---------------- pack kernel ----------------
// Per-LSTM pack: [wp(16)][kt(9)][g(4)][512]; wp = wv*2+p. Tile = B-frag of n-tile
// ntg = g*16 + wv*2 + p.  K map: k<256 Whh, 256..259 Wih, k==260 bias row, else 0.
struct PackArgs {
  const ushort_t* wih[4]; const ushort_t* whh[4];
  const ushort_t* bih[4]; const ushort_t* bhh[4];
  const ushort_t* fcsp_w; const ushort_t* fcsp_b;
  const ushort_t* fccr_w; const ushort_t* fccr_b;
  const ushort_t* emb_w;  const ushort_t* emb_b;
  ushort_t* ws;
};

__global__ void pack_kernel(PackArgs a){
  const int f32 = sniff_f32(a.whh[0]);
  int idx = blockIdx.x*256 + threadIdx.x;
  if (blockIdx.x == 0 && threadIdx.x == 0) *(int*)(a.ws + FLAG_OFS) = f32;
  const int total_w = 4*PACK_W_ELEMS;
  if (idx < total_w){
    int l = idx / PACK_W_ELEMS;
    int r = idx % PACK_W_ELEMS;
    int j = r & 7;
    int lane = (r>>3) & 63;
    int tile = r >> 9;            // (wp*9 + kt)*4 + g
    int g  = tile & 3;
    int kt = (tile >> 2) % 9;
    int wp = tile / 36;
    int p = wp & 1, wv = wp >> 1;
    int n = (g*16 + wv*2 + p)*16 + (lane & 15);
    int k = kt*32 + ((lane>>4)<<3) + j;
    ushort_t v = 0;
    if (k < 256)       v = ldw(a.whh[l], n*256 + k, f32);
    else if (k < 260)  v = ldw(a.wih[l], n*4 + (k-256), f32);
    else if (k == 260) v = f2bf(ldin(a.bih[l], n, f32) + ldin(a.bhh[l], n, f32));
    a.ws[l*PACK_W_ELEMS + r] = v;
    return;
  }
  idx -= total_w;
  if (idx < 2*HEAD_ELEMS){
    int which = idx / HEAD_ELEMS;           // 0 = speed, 1 = cross
    int r = idx % HEAD_ELEMS;
    int j = r & 7; int lane = (r>>3)&63; int kt = r>>9;
    int n = lane & 15; int k = kt*32 + ((lane>>4)<<3) + j;
    ushort_t v = 0;
    if (which == 0){
      if (n < 4){
        if (k < 256)       v = ldw(a.fcsp_w, n*256 + k, f32);
        else if (k == 260) v = f2bf(ldin(a.fcsp_b, n, f32));
      }
    } else {
      if (n < 4){
        if (k < 256)       v = ldw(a.emb_w, n*256 + k, f32);
        else if (k == 260) v = f2bf(ldin(a.emb_b, n, f32));
      } else if (n < 6){
        if (k < 256)       v = ldw(a.fccr_w, (n-4)*256 + k, f32);
        else if (k == 260) v = f2bf(ldin(a.fccr_b, n-4, f32));
      }
    }
    a.ws[total_w + idx] = v;
  }
}

// ---------------- gate math ----------------
// acc slots: gate g at gu = g*2+u  (i=0, f=1, g=2, o=3)
__device__ __forceinline__ void wb_elem(f32x4 (&acc)[4][8], float (&cw)[4][2][4],
                                        ushort_t* __restrict__ Ap, int wbBase,
                                        int u, int mt, int r){
  float cn = sigmf_(acc[mt][2+u][r])*cw[mt][u][r]
           + sigmf_(acc[mt][u][r])*tanhf_(acc[mt][4+u][r]);
  float hn = sigmf_(acc[mt][6+u][r])*tanhf_(cn);
  cw[mt][u][r] = cn;
  Ap[mt*4608 + u*256 + r*8 + wbBase] = f2bf(hn);
}

__device__ __forceinline__ void wb_u(f32x4 (&acc)[4][8], float (&cw)[4][2][4],
                                     ushort_t* __restrict__ Ap, int wbBase, int u){
  #pragma unroll
  for (int mt = 0; mt < 4; ++mt)
    #pragma unroll
    for (int r = 0; r < 4; ++r) wb_elem(acc, cw, Ap, wbBase, u, mt, r);
}

// ---- half-GEMM over parity `par`: 9 kt x 4 g tiles, double-buffered B prefetch.
// FUSE=1: interleave 2 wb elements (u=1) per kt (16 over kt 0..7) reading opposite-parity acc.
template<int FUSE>
__device__ __forceinline__ void gemm_half(const ushort_t* __restrict__ Aln,  // ApX + lane*8
                                          const ushort_t* __restrict__ bp,   // parity base + lane*8
                                          f32x4 (&acc)[4][8], int par,
                                          float (&cw)[4][2][4],
                                          ushort_t* __restrict__ ApWb, int wbBase){
  #pragma unroll
  for (int mt = 0; mt < 4; ++mt)
    #pragma unroll
    for (int g = 0; g < 4; ++g) acc[mt][g*2+par] = (f32x4){0.f,0.f,0.f,0.f};
  bf16x8 buf[2][4];
  #pragma unroll
  for (int g = 0; g < 4; ++g) buf[0][g] = *(const bf16x8*)&bp[g*512];
  #pragma unroll 1
  for (int kt = 0; kt < 9; ++kt){
    const int cur = kt & 1;
    if (kt < 8){
      const ushort_t* bn = bp + (kt+1)*2048;
      #pragma unroll
      for (int g = 0; g < 4; ++g) buf[cur^1][g] = *(const bf16x8*)&bn[g*512];
      if (FUSE){
        wb_elem(acc, cw, ApWb, wbBase, 1, kt>>1, (kt&1)*2 + 0);
        wb_elem(acc, cw, ApWb, wbBase, 1, kt>>1, (kt&1)*2 + 1);
      }
    }
    bf16x8 a0 = *(const bf16x8*)&Aln[(0*9+kt)*512];
    bf16x8 a1 = *(const bf16x8*)&Aln[(1*9+kt)*512];
    bf16x8 a2 = *(const bf16x8*)&Aln[(2*9+kt)*512];
    bf16x8 a3 = *(const bf16x8*)&Aln[(3*9+kt)*512];
    #pragma unroll
    for (int g = 0; g < 4; ++g){
      bf16x8 bv = buf[cur][g];
      acc[0][g*2+par] = __builtin_amdgcn_mfma_f32_16x16x32_bf16(a0, bv, acc[0][g*2+par], 0, 0, 0);
      acc[1][g*2+par] = __builtin_amdgcn_mfma_f32_16x16x32_bf16(a1, bv, acc[1][g*2+par], 0, 0, 0);
      acc[2][g*2+par] = __builtin_amdgcn_mfma_f32_16x16x32_bf16(a2, bv, acc[2][g*2+par], 0, 0, 0);
      acc[3][g*2+par] = __builtin_amdgcn_mfma_f32_16x16x32_bf16(a3, bv, acc[3][g*2+par], 0, 0, 0);
    }
  }
}

// ---------------- main kernel: 256 blocks x 64 rows, 512 threads (8 waves) ----------------
// Wave w owns h-cols [w*32, w*32+32) of all 4 gates, all 4 m-tiles (acc 128 AGPR).
// Region = wb(u=0) ; GEMM(p=0) with fused wb(u=1) ; GEMM(p=1) — gate VALU hidden
// under the contiguous double-buffered B stream.
__global__ __launch_bounds__(512, 2) void pvlstm_main(
    const ushort_t* __restrict__ ws,
    const ushort_t* __restrict__ speed,
    const ushort_t* __restrict__ pos,
    void* __restrict__ outv)
{
  __shared__ ushort_t ApS[4*9*512];   // A-pack speed-enc / speed-dec (36 KB)
  __shared__ ushort_t ApP[4*9*512];   // A-pack pos-enc / cross-dec   (36 KB)
  __shared__ ushort_t xsS[64*64];     // staged speed inputs (8 KB)
  __shared__ ushort_t xsP[64*64];     // staged pos inputs   (8 KB)
  __shared__ float    ostS[64*64];    // speed outputs stage (16 KB)
  __shared__ float    ostC[64*32];    // crossing outputs stage (8 KB)

  const int f32   = *(const int*)(ws + FLAG_OFS);
  const int tid   = threadIdx.x;
  const int lane  = tid & 63;
  const int w     = tid >> 6;   // 0..7
  const int col16 = lane & 15;
  const int quad  = lane >> 4;
  const int brow0 = blockIdx.x * 64;
  const int wbBase = w*512 + (col16>>3)*128 + quad*32 + (col16&7);

  ushort_t* outu = (ushort_t*)outv;
  float*    outf = (float*)outv;

  const ushort_t* headsp = ws + 4*PACK_W_ELEMS;
  const ushort_t* headcr = headsp + HEAD_ELEMS;
  const ushort_t* aS  = ApS + lane*8;
  const ushort_t* aP  = ApP + lane*8;
  // per-wave parity bases: [wp][kt][g][512], wp = w*2+p ; stride wp: 9*4*512 = 18432
  const ushort_t* bS0  = ws + 0*PACK_W_ELEMS + (size_t)(w*2+0)*18432 + (size_t)lane*8;
  const ushort_t* bS1  = ws + 0*PACK_W_ELEMS + (size_t)(w*2+1)*18432 + (size_t)lane*8;
  const ushort_t* bP0  = ws + 1*PACK_W_ELEMS + (size_t)(w*2+0)*18432 + (size_t)lane*8;
  const ushort_t* bP1  = ws + 1*PACK_W_ELEMS + (size_t)(w*2+1)*18432 + (size_t)lane*8;
  const ushort_t* bDS0 = ws + 2*PACK_W_ELEMS + (size_t)(w*2+0)*18432 + (size_t)lane*8;
  const ushort_t* bDS1 = ws + 2*PACK_W_ELEMS + (size_t)(w*2+1)*18432 + (size_t)lane*8;
  const ushort_t* bDC0 = ws + 3*PACK_W_ELEMS + (size_t)(w*2+0)*18432 + (size_t)lane*8;
  const ushort_t* bDC1 = ws + 3*PACK_W_ELEMS + (size_t)(w*2+1)*18432 + (size_t)lane*8;

  float cwA[4][2][4], cwB[4][2][4];
  f32x4 acc[4][8];

  // ---- prologue ----
  for (int i = tid; i < 4096; i += 512){
    int gi = (brow0 + (i>>6))*64 + (i&63);
    xsS[i] = f2bf(ldin(speed, gi, f32));
    xsP[i] = f2bf(ldin(pos,   gi, f32));
  }
  for (int i = tid; i < 4*9*512/2; i += 512){
    ((unsigned*)ApS)[i] = 0u; ((unsigned*)ApP)[i] = 0u;
  }
  #pragma unroll
  for (int mt = 0; mt < 4; ++mt)
    #pragma unroll
    for (int u = 0; u < 2; ++u)
      #pragma unroll
      for (int r = 0; r < 4; ++r){ cwA[mt][u][r] = 0.f; cwB[mt][u][r] = 0.f; }
  __syncthreads();
  if (tid < 64){
    ushort_t* xpS = &ApS[((tid>>4)*9 + 8)*512 + (tid&15)*8];
    ushort_t* xpP = &ApP[((tid>>4)*9 + 8)*512 + (tid&15)*8];
    *(uint2*)xpS = *(const uint2*)&xsS[tid*64];    // x_sp(0)
    xpS[4] = (ushort_t)0x3f80;                     // bias 1.0 column
    xpP[4] = (ushort_t)0x3f80;
  }
  __syncthreads();

  // ================= encoders: sp (A/cwA) and po (B/cwB), interleaved =================
  for (int t = 0; t < 16; ++t){
    // R1: wb_po(t-1) [u-split, fused] ; x_po(t) ; GEMM_sp(t)
    if (tid < 64)
      *(uint2*)&ApP[((tid>>4)*9 + 8)*512 + (tid&15)*8] = *(const uint2*)&xsP[tid*64 + t*4];
    if (t > 0){
      wb_u(acc, cwB, ApP, wbBase, 0);
      gemm_half<1>(aS, bS0, acc, 0, cwB, ApP, wbBase);
    } else {
      gemm_half<0>(aS, bS0, acc, 0, cwB, ApP, wbBase);
    }
    gemm_half<0>(aS, bS1, acc, 1, cwB, ApP, wbBase);
    __syncthreads();
    // R2: wb_sp(t) [u-split, fused] ; x_sp(t+1) ; GEMM_po(t)
    if (t < 15 && tid < 64)
      *(uint2*)&ApS[((tid>>4)*9 + 8)*512 + (tid&15)*8] = *(const uint2*)&xsS[tid*64 + t*4 + 4];
    wb_u(acc, cwA, ApS, wbBase, 0);
    gemm_half<1>(aP, bP0, acc, 0, cwA, ApS, wbBase);
    gemm_half<0>(aP, bP1, acc, 1, cwA, ApS, wbBase);
    __syncthreads();
  }
  // ---- encoder epilogue: gates_po(15); h0 = h_sp+h_po into BOTH packs; c0 in regs ----
  #pragma unroll
  for (int mt = 0; mt < 4; ++mt)
    #pragma unroll
    for (int u = 0; u < 2; ++u)
      #pragma unroll
      for (int r = 0; r < 4; ++r){
        float cn = sigmf_(acc[mt][2+u][r])*cwB[mt][u][r]
                 + sigmf_(acc[mt][u][r])*tanhf_(acc[mt][4+u][r]);
        float hn = sigmf_(acc[mt][6+u][r])*tanhf_(cn);
        float c0 = cwA[mt][u][r] + cn;
        cwA[mt][u][r] = c0; cwB[mt][u][r] = c0;
        const int ad = mt*4608 + u*256 + r*8 + wbBase;
        ushort_t h0 = f2bf(bf2f(ApS[ad]) + hn);    // own value written in R2(15)
        ApS[ad] = h0; ApP[ad] = h0;
      }
  if (tid < 64){
    *(uint2*)&ApS[((tid>>4)*9 + 8)*512 + (tid&15)*8] = *(const uint2*)&xsS[tid*64 + 60];  // x0 sp
    *(uint2*)&ApP[((tid>>4)*9 + 8)*512 + (tid&15)*8] = *(const uint2*)&xsP[tid*64 + 60];  // x0 po
  }
  __syncthreads();

  // ================= decoders: dsp (A/cwA, ApS) and dcr (B/cwB, ApP) =================
  for (int t = 0; t < 16; ++t){
    // R1: head_cr(t-1) [waves 4..7] -> ostC + x_cr(t) ; GEMM_dsp(t)
    if (t > 0 && w >= 4){
      const int mt = w - 4;
      f32x4 hacc = (f32x4){0.f,0.f,0.f,0.f};
      #pragma unroll
      for (int kt = 0; kt < 9; ++kt){
        bf16x8 a  = *(const bf16x8*)&aP[(mt*9+kt)*512];
        bf16x8 bv = *(const bf16x8*)&headcr[((size_t)kt*64 + lane)*8];
        hacc = __builtin_amdgcn_mfma_f32_16x16x32_bf16(a, bv, hacc, 0, 0, 0);
      }
      const int s = col16;
      #pragma unroll
      for (int r = 0; r < 4; ++r){
        float v = fmaxf(hacc[r], 0.f);             // relu
        const float o = __shfl_xor(v, 1, 64);      // pair logits (lanes 4<->5)
        const int m = mt*16 + quad*4 + r;
        if (s < 4){
          ApP[(mt*9+8)*512 + (m&15)*8 + s] = f2bf(v);          // x_cr(t) feedback
        } else if (s < 6){
          const float mx = fmaxf(v, o);
          const float e0 = __expf(v-mx), e1 = __expf(o-mx);
          ostC[m*32 + (t-1)*2 + (s-4)] = e0*rcp_(e0+e1);       // softmax2 at t-1
        }
      }
    }
    gemm_half<0>(aS, bDS0, acc, 0, cwB, ApP, wbBase);
    gemm_half<0>(aS, bDS1, acc, 1, cwB, ApP, wbBase);
    __syncthreads();
    // R2: wb_dsp(t) [u-split, fused] ; GEMM_dcr(t)
    wb_u(acc, cwA, ApS, wbBase, 0);
    gemm_half<1>(aP, bDC0, acc, 0, cwA, ApS, wbBase);
    gemm_half<0>(aP, bDC1, acc, 1, cwA, ApS, wbBase);
    __syncthreads();
    // R3: wb_dcr(t) ; head_sp(t) [waves 0..3] -> ostS + x_sp(t+1)
    wb_u(acc, cwB, ApP, wbBase, 0);
    wb_u(acc, cwB, ApP, wbBase, 1);
    if (w < 4){
      const int mt = w;
      f32x4 hacc = (f32x4){0.f,0.f,0.f,0.f};
      #pragma unroll
      for (int kt = 0; kt < 9; ++kt){
        bf16x8 a  = *(const bf16x8*)&aS[(mt*9+kt)*512];
        bf16x8 bv = *(const bf16x8*)&headsp[((size_t)kt*64 + lane)*8];
        hacc = __builtin_amdgcn_mfma_f32_16x16x32_bf16(a, bv, hacc, 0, 0, 0);
      }
      const int s = col16;
      if (s < 4){
        #pragma unroll
        for (int r = 0; r < 4; ++r){
          float v = fminf(fmaxf(hacc[r], -100.f), 100.f);      // hardtanh(+-100)
          const int m = mt*16 + quad*4 + r;
          ostS[m*64 + t*4 + s] = v;
          ApS[(mt*9+8)*512 + (m&15)*8 + s] = f2bf(v);          // x_sp(t+1) feedback
        }
      }
    }
    __syncthreads();
  }
  // ---- decoder epilogue: head_cr(15) ----
  if (w >= 4){
    const int mt = w - 4;
    f32x4 hacc = (f32x4){0.f,0.f,0.f,0.f};
    #pragma unroll
    for (int kt = 0; kt < 9; ++kt){
      bf16x8 a  = *(const bf16x8*)&aP[(mt*9+kt)*512];
      bf16x8 bv = *(const bf16x8*)&headcr[((size_t)kt*64 + lane)*8];
      hacc = __builtin_amdgcn_mfma_f32_16x16x32_bf16(a, bv, hacc, 0, 0, 0);
    }
    const int s = col16;
    if (s >= 4 && s < 6){
      #pragma unroll
      for (int r = 0; r < 4; ++r){
        float v = fmaxf(hacc[r], 0.f);
        const float o = __shfl_xor(v, 1, 64);
        const int m = mt*16 + quad*4 + r;
        const float mx = fmaxf(v, o);
        const float e0 = __expf(v-mx), e1 = __expf(o-mx);
        ostC[m*32 + 15*2 + (s-4)] = e0*rcp_(e0+e1);
      }
    }
  }
  __syncthreads();

  // ---- coalesced output flush ----
  for (int i = tid; i < 4096; i += 512){
    const int oi = (brow0 + (i>>6))*64 + (i&63);
    const float v = ostS[i];
    if (f32) outf[oi] = v; else outu[oi] = f2bf(v);
  }
  for (int i = tid; i < 2048; i += 512){
    const int oi = 1048576 + (brow0 + (i>>5))*32 + (i&31);
    const float v = ostC[i];
    if (f32) outf[oi] = v; else outu[oi] = f2bf(v);
  }
}

extern "C" void kernel_launch(void* const* d_in, const int* in_sizes, int n_in,
                              void* d_out, int out_size, void* d_ws, size_t ws_size,
                              hipStream_t stream) {
  PackArgs pa;
  pa.wih[0]=(const ushort_t*)d_in[2];  pa.whh[0]=(const ushort_t*)d_in[3];
  pa.bih[0]=(const ushort_t*)d_in[4];  pa.bhh[0]=(const ushort_t*)d_in[5];
  pa.wih[1]=(const ushort_t*)d_in[6];  pa.whh[1]=(const ushort_t*)d_in[7];
  pa.bih[1]=(const ushort_t*)d_in[8];  pa.bhh[1]=(const ushort_t*)d_in[9];
  pa.wih[2]=(const ushort_t*)d_in[10]; pa.whh[2]=(const ushort_t*)d_in[11];
  pa.bih[2]=(const ushort_t*)d_in[12]; pa.bhh[2]=(const ushort_t*)d_in[13];
  pa.wih[3]=(const ushort_t*)d_in[14]; pa.whh[3]=(const ushort_t*)d_in[15];
  pa.bih[3]=(const ushort_t*)d_in[16]; pa.bhh[3]=(const ushort_t*)d_in[17];
  pa.fcsp_w=(const ushort_t*)d_in[18]; pa.fcsp_b=(const ushort_t*)d_in[19];
  pa.fccr_w=(const ushort_t*)d_in[20]; pa.fccr_b=(const ushort_t*)d_in[21];
  pa.emb_w =(const ushort_t*)d_in[22]; pa.emb_b =(const ushort_t*)d_in[23];
  pa.ws = (ushort_t*)d_ws;

  hipLaunchKernelGGL(pack_kernel, dim3((PACK_TOTAL + 255)/256), dim3(256), 0, stream, pa);
  hipLaunchKernelGGL(pvlstm_main, dim3(256), dim3(512), 0, stream,
      (const ushort_t*)d_ws,
      (const ushort_t*)d_in[0], (const ushort_t*)d_in[1],
      d_out);
}

// Round 9
// 3507.674 us; speedup vs baseline: 1.1374x; 1.1374x over previous
//
#include <hip/hip_runtime.h>

typedef unsigned short ushort_t;
typedef __bf16 bf16x8 __attribute__((ext_vector_type(8)));
typedef float f32x4 __attribute__((ext_vector_type(4)));

#define PACK_W_ELEMS (16*9*4*512)          // 294912 bf16 per LSTM: [wp16=wv*2+p][kt9][g4][512]
#define HEAD_ELEMS   (9*512)               // 1 n-tile x 9 k-tiles
#define PACK_TOTAL   (4*PACK_W_ELEMS + 2*HEAD_ELEMS)
#define FLAG_OFS     PACK_TOTAL            // ushort index of int dtype flag

__device__ __forceinline__ float bf2f(ushort_t u){ return __uint_as_float(((unsigned)u)<<16); }
__device__ __forceinline__ ushort_t f2bf(float f){
  __bf16 h = (__bf16)f;                    // HW RTNE convert (values bounded)
  return *(ushort_t*)&h;
}
__device__ __forceinline__ float rcp_(float x){ return __builtin_amdgcn_rcpf(x); }
__device__ __forceinline__ float sigmf_(float x){ return rcp_(1.0f + __expf(-x)); }
__device__ __forceinline__ float tanhf_(float x){ return 1.0f - 2.0f*rcp_(1.0f + __expf(2.0f*x)); }

__device__ __forceinline__ int sniff_f32(const ushort_t* w){
  int f32 = 0;
  #pragma unroll
  for (int i = 0; i < 32; ++i){
    float f = bf2f(w[2*i]);
    if (!(f > -8.f && f < 8.f)) f32 = 1;
  }
  return f32;
}
__device__ __forceinline__ float ldin(const ushort_t* p, int i, int f32){
  return f32 ? ((const float*)p)[i] : bf2f(p[i]);
}
__device__ __forceinline__ ushort_t ldw(const ushort_t* p, int i, int f32){
  return f32 ? f2bf(((const float*)p)[i]) : p[i];
}

// ---------------- pack kernel ----------------
// Per-LSTM pack: [wp(16)][kt(9)][g(4)][512]; wp = wv*2+p. Tile = B-frag of n-tile
// ntg = g*16 + wv*2 + p.  K map: k<256 Whh, 256..259 Wih, k==260 bias row, else 0.
struct PackArgs {
  const ushort_t* wih[4]; const ushort_t* whh[4];
  const ushort_t* bih[4]; const ushort_t* bhh[4];
  const ushort_t* fcsp_w; const ushort_t* fcsp_b;
  const ushort_t* fccr_w; const ushort_t* fccr_b;
  const ushort_t* emb_w;  const ushort_t* emb_b;
  ushort_t* ws;
};

__global__ void pack_kernel(PackArgs a){
  const int f32 = sniff_f32(a.whh[0]);
  int idx = blockIdx.x*256 + threadIdx.x;
  if (blockIdx.x == 0 && threadIdx.x == 0) *(int*)(a.ws + FLAG_OFS) = f32;
  const int total_w = 4*PACK_W_ELEMS;
  if (idx < total_w){
    int l = idx / PACK_W_ELEMS;
    int r = idx % PACK_W_ELEMS;
    int j = r & 7;
    int lane = (r>>3) & 63;
    int tile = r >> 9;            // (wp*9 + kt)*4 + g
    int g  = tile & 3;
    int kt = (tile >> 2) % 9;
    int wp = tile / 36;
    int p = wp & 1, wv = wp >> 1;
    int n = (g*16 + wv*2 + p)*16 + (lane & 15);
    int k = kt*32 + ((lane>>4)<<3) + j;
    ushort_t v = 0;
    if (k < 256)       v = ldw(a.whh[l], n*256 + k, f32);
    else if (k < 260)  v = ldw(a.wih[l], n*4 + (k-256), f32);
    else if (k == 260) v = f2bf(ldin(a.bih[l], n, f32) + ldin(a.bhh[l], n, f32));
    a.ws[l*PACK_W_ELEMS + r] = v;
    return;
  }
  idx -= total_w;
  if (idx < 2*HEAD_ELEMS){
    int which = idx / HEAD_ELEMS;           // 0 = speed, 1 = cross
    int r = idx % HEAD_ELEMS;
    int j = r & 7; int lane = (r>>3)&63; int kt = r>>9;
    int n = lane & 15; int k = kt*32 + ((lane>>4)<<3) + j;
    ushort_t v = 0;
    if (which == 0){
      if (n < 4){
        if (k < 256)       v = ldw(a.fcsp_w, n*256 + k, f32);
        else if (k == 260) v = f2bf(ldin(a.fcsp_b, n, f32));
      }
    } else {
      if (n < 4){
        if (k < 256)       v = ldw(a.emb_w, n*256 + k, f32);
        else if (k == 260) v = f2bf(ldin(a.emb_b, n, f32));
      } else if (n < 6){
        if (k < 256)       v = ldw(a.fccr_w, (n-4)*256 + k, f32);
        else if (k == 260) v = f2bf(ldin(a.fccr_b, n-4, f32));
      }
    }
    a.ws[total_w + idx] = v;
  }
}

// ---------------- gate math ----------------
// acc slots: gate g at index g*2+u  (i=0, f=1, g=2, o=3); u=0 even slots, u=1 odd slots.
// ALL indices are template constants (register residency).
template<int U, int MT, int R>
__device__ __forceinline__ void wb_elem(f32x4 (&acc)[4][8], float (&cw)[4][2][4],
                                        ushort_t* __restrict__ Ap, int wbBase){
  float cn = sigmf_(acc[MT][2+U][R])*cw[MT][U][R]
           + sigmf_(acc[MT][U][R])*tanhf_(acc[MT][4+U][R]);
  float hn = sigmf_(acc[MT][6+U][R])*tanhf_(cn);
  cw[MT][U][R] = cn;
  Ap[MT*4608 + U*256 + R*8 + wbBase] = f2bf(hn);
}

template<int U>
__device__ __forceinline__ void wb_u(f32x4 (&acc)[4][8], float (&cw)[4][2][4],
                                     ushort_t* __restrict__ Ap, int wbBase){
  #pragma unroll
  for (int mt = 0; mt < 4; ++mt)
    #pragma unroll
    for (int r = 0; r < 4; ++r){
      float cn = sigmf_(acc[mt][2+U][r])*cw[mt][U][r]
               + sigmf_(acc[mt][U][r])*tanhf_(acc[mt][4+U][r]);
      float hn = sigmf_(acc[mt][6+U][r])*tanhf_(cn);
      cw[mt][U][r] = cn;
      Ap[mt*4608 + U*256 + r*8 + wbBase] = f2bf(hn);
    }
}

// one kt step: 4 B loads, (FUSE) 2 fused wb elems (u=1), 4 A loads, 16 MFMAs
template<int FUSE, int PAR, int KT>
__device__ __forceinline__ void kt_step(const ushort_t* __restrict__ Aln,
                                        const ushort_t* __restrict__ bp,
                                        f32x4 (&acc)[4][8], float (&cw)[4][2][4],
                                        ushort_t* __restrict__ ApWb, int wbBase){
  bf16x8 b0 = *(const bf16x8*)&bp[KT*2048 + 0*512];
  bf16x8 b1 = *(const bf16x8*)&bp[KT*2048 + 1*512];
  bf16x8 b2 = *(const bf16x8*)&bp[KT*2048 + 2*512];
  bf16x8 b3 = *(const bf16x8*)&bp[KT*2048 + 3*512];
  if constexpr (FUSE && KT < 8){
    wb_elem<1, (KT>>1), ((KT&1)*2+0)>(acc, cw, ApWb, wbBase);
    wb_elem<1, (KT>>1), ((KT&1)*2+1)>(acc, cw, ApWb, wbBase);
  }
  bf16x8 a0 = *(const bf16x8*)&Aln[(0*9+KT)*512];
  bf16x8 a1 = *(const bf16x8*)&Aln[(1*9+KT)*512];
  bf16x8 a2 = *(const bf16x8*)&Aln[(2*9+KT)*512];
  bf16x8 a3 = *(const bf16x8*)&Aln[(3*9+KT)*512];
  acc[0][0*2+PAR] = __builtin_amdgcn_mfma_f32_16x16x32_bf16(a0, b0, acc[0][0*2+PAR], 0, 0, 0);
  acc[1][0*2+PAR] = __builtin_amdgcn_mfma_f32_16x16x32_bf16(a1, b0, acc[1][0*2+PAR], 0, 0, 0);
  acc[2][0*2+PAR] = __builtin_amdgcn_mfma_f32_16x16x32_bf16(a2, b0, acc[2][0*2+PAR], 0, 0, 0);
  acc[3][0*2+PAR] = __builtin_amdgcn_mfma_f32_16x16x32_bf16(a3, b0, acc[3][0*2+PAR], 0, 0, 0);
  acc[0][1*2+PAR] = __builtin_amdgcn_mfma_f32_16x16x32_bf16(a0, b1, acc[0][1*2+PAR], 0, 0, 0);
  acc[1][1*2+PAR] = __builtin_amdgcn_mfma_f32_16x16x32_bf16(a1, b1, acc[1][1*2+PAR], 0, 0, 0);
  acc[2][1*2+PAR] = __builtin_amdgcn_mfma_f32_16x16x32_bf16(a2, b1, acc[2][1*2+PAR], 0, 0, 0);
  acc[3][1*2+PAR] = __builtin_amdgcn_mfma_f32_16x16x32_bf16(a3, b1, acc[3][1*2+PAR], 0, 0, 0);
  acc[0][2*2+PAR] = __builtin_amdgcn_mfma_f32_16x16x32_bf16(a0, b2, acc[0][2*2+PAR], 0, 0, 0);
  acc[1][2*2+PAR] = __builtin_amdgcn_mfma_f32_16x16x32_bf16(a1, b2, acc[1][2*2+PAR], 0, 0, 0);
  acc[2][2*2+PAR] = __builtin_amdgcn_mfma_f32_16x16x32_bf16(a2, b2, acc[2][2*2+PAR], 0, 0, 0);
  acc[3][2*2+PAR] = __builtin_amdgcn_mfma_f32_16x16x32_bf16(a3, b2, acc[3][2*2+PAR], 0, 0, 0);
  acc[0][3*2+PAR] = __builtin_amdgcn_mfma_f32_16x16x32_bf16(a0, b3, acc[0][3*2+PAR], 0, 0, 0);
  acc[1][3*2+PAR] = __builtin_amdgcn_mfma_f32_16x16x32_bf16(a1, b3, acc[1][3*2+PAR], 0, 0, 0);
  acc[2][3*2+PAR] = __builtin_amdgcn_mfma_f32_16x16x32_bf16(a2, b3, acc[2][3*2+PAR], 0, 0, 0);
  acc[3][3*2+PAR] = __builtin_amdgcn_mfma_f32_16x16x32_bf16(a3, b3, acc[3][3*2+PAR], 0, 0, 0);
}

// ---- half-GEMM over parity PAR: 9 kt x 4 g tiles, compile-time unrolled.
// FUSE=1: 2 wb elements (u=1, odd acc slots) per kt for kt=0..7, reading the opposite
// parity's finalized accumulators while this GEMM writes parity-PAR slots.
template<int FUSE, int PAR>
__device__ __forceinline__ void gemm_half(const ushort_t* __restrict__ Aln,  // ApX + lane*8
                                          const ushort_t* __restrict__ bp,   // parity base + lane*8
                                          f32x4 (&acc)[4][8],
                                          float (&cw)[4][2][4],
                                          ushort_t* __restrict__ ApWb, int wbBase){
  #pragma unroll
  for (int mt = 0; mt < 4; ++mt)
    #pragma unroll
    for (int g = 0; g < 4; ++g) acc[mt][g*2+PAR] = (f32x4){0.f,0.f,0.f,0.f};
  kt_step<FUSE,PAR,0>(Aln, bp, acc, cw, ApWb, wbBase);
  kt_step<FUSE,PAR,1>(Aln, bp, acc, cw, ApWb, wbBase);
  kt_step<FUSE,PAR,2>(Aln, bp, acc, cw, ApWb, wbBase);
  kt_step<FUSE,PAR,3>(Aln, bp, acc, cw, ApWb, wbBase);
  kt_step<FUSE,PAR,4>(Aln, bp, acc, cw, ApWb, wbBase);
  kt_step<FUSE,PAR,5>(Aln, bp, acc, cw, ApWb, wbBase);
  kt_step<FUSE,PAR,6>(Aln, bp, acc, cw, ApWb, wbBase);
  kt_step<FUSE,PAR,7>(Aln, bp, acc, cw, ApWb, wbBase);
  kt_step<FUSE,PAR,8>(Aln, bp, acc, cw, ApWb, wbBase);
}

// ---------------- main kernel: 256 blocks x 64 rows, 512 threads (8 waves) ----------------
// Wave w owns h-cols [w*32, w*32+32) of all 4 gates, all 4 m-tiles (acc 128 AGPR).
// Region = wb(u=0) ; GEMM(p=0) with fused wb(u=1) ; GEMM(p=1) — gate VALU hidden
// under the contiguous B stream.
__global__ __launch_bounds__(512, 2) void pvlstm_main(
    const ushort_t* __restrict__ ws,
    const ushort_t* __restrict__ speed,
    const ushort_t* __restrict__ pos,
    void* __restrict__ outv)
{
  __shared__ ushort_t ApS[4*9*512];   // A-pack speed-enc / speed-dec (36 KB)
  __shared__ ushort_t ApP[4*9*512];   // A-pack pos-enc / cross-dec   (36 KB)
  __shared__ ushort_t xsS[64*64];     // staged speed inputs (8 KB)
  __shared__ ushort_t xsP[64*64];     // staged pos inputs   (8 KB)
  __shared__ float    ostS[64*64];    // speed outputs stage (16 KB)
  __shared__ float    ostC[64*32];    // crossing outputs stage (8 KB)

  const int f32   = *(const int*)(ws + FLAG_OFS);
  const int tid   = threadIdx.x;
  const int lane  = tid & 63;
  const int w     = tid >> 6;   // 0..7
  const int col16 = lane & 15;
  const int quad  = lane >> 4;
  const int brow0 = blockIdx.x * 64;
  const int wbBase = w*512 + (col16>>3)*128 + quad*32 + (col16&7);

  ushort_t* outu = (ushort_t*)outv;
  float*    outf = (float*)outv;

  const ushort_t* headsp = ws + 4*PACK_W_ELEMS;
  const ushort_t* headcr = headsp + HEAD_ELEMS;
  const ushort_t* aS  = ApS + lane*8;
  const ushort_t* aP  = ApP + lane*8;
  // per-wave parity bases: [wp][kt][g][512], wp = w*2+p ; stride wp: 9*4*512 = 18432
  const ushort_t* bS0  = ws + 0*PACK_W_ELEMS + (size_t)(w*2+0)*18432 + (size_t)lane*8;
  const ushort_t* bS1  = ws + 0*PACK_W_ELEMS + (size_t)(w*2+1)*18432 + (size_t)lane*8;
  const ushort_t* bP0  = ws + 1*PACK_W_ELEMS + (size_t)(w*2+0)*18432 + (size_t)lane*8;
  const ushort_t* bP1  = ws + 1*PACK_W_ELEMS + (size_t)(w*2+1)*18432 + (size_t)lane*8;
  const ushort_t* bDS0 = ws + 2*PACK_W_ELEMS + (size_t)(w*2+0)*18432 + (size_t)lane*8;
  const ushort_t* bDS1 = ws + 2*PACK_W_ELEMS + (size_t)(w*2+1)*18432 + (size_t)lane*8;
  const ushort_t* bDC0 = ws + 3*PACK_W_ELEMS + (size_t)(w*2+0)*18432 + (size_t)lane*8;
  const ushort_t* bDC1 = ws + 3*PACK_W_ELEMS + (size_t)(w*2+1)*18432 + (size_t)lane*8;

  float cwA[4][2][4], cwB[4][2][4];
  f32x4 acc[4][8];

  // ---- prologue ----
  for (int i = tid; i < 4096; i += 512){
    int gi = (brow0 + (i>>6))*64 + (i&63);
    xsS[i] = f2bf(ldin(speed, gi, f32));
    xsP[i] = f2bf(ldin(pos,   gi, f32));
  }
  for (int i = tid; i < 4*9*512/2; i += 512){
    ((unsigned*)ApS)[i] = 0u; ((unsigned*)ApP)[i] = 0u;
  }
  #pragma unroll
  for (int mt = 0; mt < 4; ++mt)
    #pragma unroll
    for (int u = 0; u < 2; ++u)
      #pragma unroll
      for (int r = 0; r < 4; ++r){ cwA[mt][u][r] = 0.f; cwB[mt][u][r] = 0.f; }
  __syncthreads();
  if (tid < 64){
    ushort_t* xpS = &ApS[((tid>>4)*9 + 8)*512 + (tid&15)*8];
    ushort_t* xpP = &ApP[((tid>>4)*9 + 8)*512 + (tid&15)*8];
    *(uint2*)xpS = *(const uint2*)&xsS[tid*64];    // x_sp(0)
    xpS[4] = (ushort_t)0x3f80;                     // bias 1.0 column
    xpP[4] = (ushort_t)0x3f80;
  }
  __syncthreads();

  // ================= encoders: sp (A/cwA) and po (B/cwB), interleaved =================
  for (int t = 0; t < 16; ++t){
    // R1: wb_po(t-1) [u-split, fused] ; x_po(t) ; GEMM_sp(t)
    if (tid < 64)
      *(uint2*)&ApP[((tid>>4)*9 + 8)*512 + (tid&15)*8] = *(const uint2*)&xsP[tid*64 + t*4];
    if (t > 0){
      wb_u<0>(acc, cwB, ApP, wbBase);
      gemm_half<1,0>(aS, bS0, acc, cwB, ApP, wbBase);
    } else {
      gemm_half<0,0>(aS, bS0, acc, cwB, ApP, wbBase);
    }
    gemm_half<0,1>(aS, bS1, acc, cwB, ApP, wbBase);
    __syncthreads();
    // R2: wb_sp(t) [u-split, fused] ; x_sp(t+1) ; GEMM_po(t)
    if (t < 15 && tid < 64)
      *(uint2*)&ApS[((tid>>4)*9 + 8)*512 + (tid&15)*8] = *(const uint2*)&xsS[tid*64 + t*4 + 4];
    wb_u<0>(acc, cwA, ApS, wbBase);
    gemm_half<1,0>(aP, bP0, acc, cwA, ApS, wbBase);
    gemm_half<0,1>(aP, bP1, acc, cwA, ApS, wbBase);
    __syncthreads();
  }
  // ---- encoder epilogue: gates_po(15); h0 = h_sp+h_po into BOTH packs; c0 in regs ----
  #pragma unroll
  for (int mt = 0; mt < 4; ++mt)
    #pragma unroll
    for (int u = 0; u < 2; ++u)
      #pragma unroll
      for (int r = 0; r < 4; ++r){
        float cn = sigmf_(acc[mt][2+u][r])*cwB[mt][u][r]
                 + sigmf_(acc[mt][u][r])*tanhf_(acc[mt][4+u][r]);
        float hn = sigmf_(acc[mt][6+u][r])*tanhf_(cn);
        float c0 = cwA[mt][u][r] + cn;
        cwA[mt][u][r] = c0; cwB[mt][u][r] = c0;
        const int ad = mt*4608 + u*256 + r*8 + wbBase;
        ushort_t h0 = f2bf(bf2f(ApS[ad]) + hn);    // own value written in R2(15)
        ApS[ad] = h0; ApP[ad] = h0;
      }
  if (tid < 64){
    *(uint2*)&ApS[((tid>>4)*9 + 8)*512 + (tid&15)*8] = *(const uint2*)&xsS[tid*64 + 60];  // x0 sp
    *(uint2*)&ApP[((tid>>4)*9 + 8)*512 + (tid&15)*8] = *(const uint2*)&xsP[tid*64 + 60];  // x0 po
  }
  __syncthreads();

  // ================= decoders: dsp (A/cwA, ApS) and dcr (B/cwB, ApP) =================
  for (int t = 0; t < 16; ++t){
    // R1: head_cr(t-1) [waves 4..7] -> ostC + x_cr(t) ; GEMM_dsp(t)
    if (t > 0 && w >= 4){
      const int mt = w - 4;
      f32x4 hacc = (f32x4){0.f,0.f,0.f,0.f};
      #pragma unroll
      for (int kt = 0; kt < 9; ++kt){
        bf16x8 a  = *(const bf16x8*)&aP[(mt*9+kt)*512];
        bf16x8 bv = *(const bf16x8*)&headcr[((size_t)kt*64 + lane)*8];
        hacc = __builtin_amdgcn_mfma_f32_16x16x32_bf16(a, bv, hacc, 0, 0, 0);
      }
      const int s = col16;
      #pragma unroll
      for (int r = 0; r < 4; ++r){
        float v = fmaxf(hacc[r], 0.f);             // relu
        const float o = __shfl_xor(v, 1, 64);      // pair logits (lanes 4<->5)
        const int m = mt*16 + quad*4 + r;
        if (s < 4){
          ApP[(mt*9+8)*512 + (m&15)*8 + s] = f2bf(v);          // x_cr(t) feedback
        } else if (s < 6){
          const float mx = fmaxf(v, o);
          const float e0 = __expf(v-mx), e1 = __expf(o-mx);
          ostC[m*32 + (t-1)*2 + (s-4)] = e0*rcp_(e0+e1);       // softmax2 at t-1
        }
      }
    }
    gemm_half<0,0>(aS, bDS0, acc, cwB, ApP, wbBase);
    gemm_half<0,1>(aS, bDS1, acc, cwB, ApP, wbBase);
    __syncthreads();
    // R2: wb_dsp(t) [u-split, fused] ; GEMM_dcr(t)
    wb_u<0>(acc, cwA, ApS, wbBase);
    gemm_half<1,0>(aP, bDC0, acc, cwA, ApS, wbBase);
    gemm_half<0,1>(aP, bDC1, acc, cwA, ApS, wbBase);
    __syncthreads();
    // R3: wb_dcr(t) ; head_sp(t) [waves 0..3] -> ostS + x_sp(t+1)
    wb_u<0>(acc, cwB, ApP, wbBase);
    wb_u<1>(acc, cwB, ApP, wbBase);
    if (w < 4){
      const int mt = w;
      f32x4 hacc = (f32x4){0.f,0.f,0.f,0.f};
      #pragma unroll
      for (int kt = 0; kt < 9; ++kt){
        bf16x8 a  = *(const bf16x8*)&aS[(mt*9+kt)*512];
        bf16x8 bv = *(const bf16x8*)&headsp[((size_t)kt*64 + lane)*8];
        hacc = __builtin_amdgcn_mfma_f32_16x16x32_bf16(a, bv, hacc, 0, 0, 0);
      }
      const int s = col16;
      if (s < 4){
        #pragma unroll
        for (int r = 0; r < 4; ++r){
          float v = fminf(fmaxf(hacc[r], -100.f), 100.f);      // hardtanh(+-100)
          const int m = mt*16 + quad*4 + r;
          ostS[m*64 + t*4 + s] = v;
          ApS[(mt*9+8)*512 + (m&15)*8 + s] = f2bf(v);          // x_sp(t+1) feedback
        }
      }
    }
    __syncthreads();
  }
  // ---- decoder epilogue: head_cr(15) ----
  if (w >= 4){
    const int mt = w - 4;
    f32x4 hacc = (f32x4){0.f,0.f,0.f,0.f};
    #pragma unroll
    for (int kt = 0; kt < 9; ++kt){
      bf16x8 a  = *(const bf16x8*)&aP[(mt*9+kt)*512];
      bf16x8 bv = *(const bf16x8*)&headcr[((size_t)kt*64 + lane)*8];
      hacc = __builtin_amdgcn_mfma_f32_16x16x32_bf16(a, bv, hacc, 0, 0, 0);
    }
    const int s = col16;
    if (s >= 4 && s < 6){
      #pragma unroll
      for (int r = 0; r < 4; ++r){
        float v = fmaxf(hacc[r], 0.f);
        const float o = __shfl_xor(v, 1, 64);
        const int m = mt*16 + quad*4 + r;
        const float mx = fmaxf(v, o);
        const float e0 = __expf(v-mx), e1 = __expf(o-mx);
        ostC[m*32 + 15*2 + (s-4)] = e0*rcp_(e0+e1);
      }
    }
  }
  __syncthreads();

  // ---- coalesced output flush ----
  for (int i = tid; i < 4096; i += 512){
    const int oi = (brow0 + (i>>6))*64 + (i&63);
    const float v = ostS[i];
    if (f32) outf[oi] = v; else outu[oi] = f2bf(v);
  }
  for (int i = tid; i < 2048; i += 512){
    const int oi = 1048576 + (brow0 + (i>>5))*32 + (i&31);
    const float v = ostC[i];
    if (f32) outf[oi] = v; else outu[oi] = f2bf(v);
  }
}

extern "C" void kernel_launch(void* const* d_in, const int* in_sizes, int n_in,
                              void* d_out, int out_size, void* d_ws, size_t ws_size,
                              hipStream_t stream) {
  PackArgs pa;
  pa.wih[0]=(const ushort_t*)d_in[2];  pa.whh[0]=(const ushort_t*)d_in[3];
  pa.bih[0]=(const ushort_t*)d_in[4];  pa.bhh[0]=(const ushort_t*)d_in[5];
  pa.wih[1]=(const ushort_t*)d_in[6];  pa.whh[1]=(const ushort_t*)d_in[7];
  pa.bih[1]=(const ushort_t*)d_in[8];  pa.bhh[1]=(const ushort_t*)d_in[9];
  pa.wih[2]=(const ushort_t*)d_in[10]; pa.whh[2]=(const ushort_t*)d_in[11];
  pa.bih[2]=(const ushort_t*)d_in[12]; pa.bhh[2]=(const ushort_t*)d_in[13];
  pa.wih[3]=(const ushort_t*)d_in[14]; pa.whh[3]=(const ushort_t*)d_in[15];
  pa.bih[3]=(const ushort_t*)d_in[16]; pa.bhh[3]=(const ushort_t*)d_in[17];
  pa.fcsp_w=(const ushort_t*)d_in[18]; pa.fcsp_b=(const ushort_t*)d_in[19];
  pa.fccr_w=(const ushort_t*)d_in[20]; pa.fccr_b=(const ushort_t*)d_in[21];
  pa.emb_w =(const ushort_t*)d_in[22]; pa.emb_b =(const ushort_t*)d_in[23];
  pa.ws = (ushort_t*)d_ws;

  hipLaunchKernelGGL(pack_kernel, dim3((PACK_TOTAL + 255)/256), dim3(256), 0, stream, pa);
  hipLaunchKernelGGL(pvlstm_main, dim3(256), dim3(512), 0, stream,
      (const ushort_t*)d_ws,
      (const ushort_t*)d_in[0], (const ushort_t*)d_in[1],
      d_out);
}

// Round 10
// 850.482 us; speedup vs baseline: 4.6909x; 4.1243x over previous
//
#include <hip/hip_runtime.h>

typedef unsigned short ushort_t;
typedef __bf16 bf16x8 __attribute__((ext_vector_type(8)));
typedef float f32x4 __attribute__((ext_vector_type(4)));

#define PACK_W_ELEMS (8*9*8*512)           // 294912 bf16 per LSTM: [wave8][kt9][gu8][512]
#define HEAD_ELEMS   (9*512)               // 1 n-tile x 9 k-tiles
#define PACK_TOTAL   (4*PACK_W_ELEMS + 2*HEAD_ELEMS)
#define FLAG_OFS     PACK_TOTAL            // ushort index of int dtype flag

__device__ __forceinline__ float bf2f(ushort_t u){ return __uint_as_float(((unsigned)u)<<16); }
__device__ __forceinline__ ushort_t f2bf(float f){
  __bf16 h = (__bf16)f;                    // HW RTNE convert (values bounded)
  return *(ushort_t*)&h;
}
__device__ __forceinline__ float rcp_(float x){ return __builtin_amdgcn_rcpf(x); }
__device__ __forceinline__ float sigmf_(float x){ return rcp_(1.0f + __expf(-x)); }
__device__ __forceinline__ float tanhf_(float x){ return 1.0f - 2.0f*rcp_(1.0f + __expf(2.0f*x)); }

__device__ __forceinline__ int sniff_f32(const ushort_t* w){
  int f32 = 0;
  #pragma unroll
  for (int i = 0; i < 32; ++i){
    float f = bf2f(w[2*i]);
    if (!(f > -8.f && f < 8.f)) f32 = 1;
  }
  return f32;
}
__device__ __forceinline__ float ldin(const ushort_t* p, int i, int f32){
  return f32 ? ((const float*)p)[i] : bf2f(p[i]);
}
__device__ __forceinline__ ushort_t ldw(const ushort_t* p, int i, int f32){
  return f32 ? f2bf(((const float*)p)[i]) : p[i];
}

// ---------------- pack kernel ----------------
// Per-LSTM pack: [wv(8)][kt(9)][gu(8)][512]; tile (wv,kt,g,u) = B-frag of n-tile
// ntg = g*16 + wv*2 + u.  K map: k<256 Whh, 256..259 Wih, k==260 bias row (bih+bhh), else 0.
struct PackArgs {
  const ushort_t* wih[4]; const ushort_t* whh[4];
  const ushort_t* bih[4]; const ushort_t* bhh[4];
  const ushort_t* fcsp_w; const ushort_t* fcsp_b;
  const ushort_t* fccr_w; const ushort_t* fccr_b;
  const ushort_t* emb_w;  const ushort_t* emb_b;
  ushort_t* ws;
};

__global__ void pack_kernel(PackArgs a){
  const int f32 = sniff_f32(a.whh[0]);
  int idx = blockIdx.x*256 + threadIdx.x;
  if (blockIdx.x == 0 && threadIdx.x == 0) *(int*)(a.ws + FLAG_OFS) = f32;
  const int total_w = 4*PACK_W_ELEMS;
  if (idx < total_w){
    int l = idx / PACK_W_ELEMS;
    int r = idx % PACK_W_ELEMS;
    int j = r & 7;
    int lane = (r>>3) & 63;
    int tile = r >> 9;            // (wv*9 + kt)*8 + gu
    int gu = tile & 7;
    int kt = (tile >> 3) % 9;
    int wv = tile / 72;
    int g = gu >> 1, u = gu & 1;
    int n = (g*16 + wv*2 + u)*16 + (lane & 15);
    int k = kt*32 + ((lane>>4)<<3) + j;
    ushort_t v = 0;
    if (k < 256)       v = ldw(a.whh[l], n*256 + k, f32);
    else if (k < 260)  v = ldw(a.wih[l], n*4 + (k-256), f32);
    else if (k == 260) v = f2bf(ldin(a.bih[l], n, f32) + ldin(a.bhh[l], n, f32));
    a.ws[l*PACK_W_ELEMS + r] = v;
    return;
  }
  idx -= total_w;
  if (idx < 2*HEAD_ELEMS){
    int which = idx / HEAD_ELEMS;           // 0 = speed, 1 = cross
    int r = idx % HEAD_ELEMS;
    int j = r & 7; int lane = (r>>3)&63; int kt = r>>9;
    int n = lane & 15; int k = kt*32 + ((lane>>4)<<3) + j;
    ushort_t v = 0;
    if (which == 0){
      if (n < 4){
        if (k < 256)       v = ldw(a.fcsp_w, n*256 + k, f32);
        else if (k == 260) v = f2bf(ldin(a.fcsp_b, n, f32));
      }
    } else {
      if (n < 4){
        if (k < 256)       v = ldw(a.emb_w, n*256 + k, f32);
        else if (k == 260) v = f2bf(ldin(a.emb_b, n, f32));
      } else if (n < 6){
        if (k < 256)       v = ldw(a.fccr_w, (n-4)*256 + k, f32);
        else if (k == 260) v = f2bf(ldin(a.fccr_b, n-4, f32));
      }
    }
    a.ws[total_w + idx] = v;
  }
}

// ---------------- device helpers for the main kernel ----------------
// Software-pipelined gate GEMM: loads run one half-kt group (4 tiles) ahead of their
// MFMAs; peak live B regs = 32 (two groups) + A 16 — same footprint as the r6 baseline.
// acc indices are all compile-time constants (register residency).
__device__ __forceinline__ void gate_gemm(const ushort_t* __restrict__ Aln,   // ApX + lane*8
                                          const ushort_t* __restrict__ bw,   // wave pack + lane*8
                                          f32x4 (&acc)[4][8], int lane){
  #pragma unroll
  for (int i = 0; i < 4; ++i)
    #pragma unroll
    for (int j = 0; j < 8; ++j) acc[i][j] = (f32x4){0.f,0.f,0.f,0.f};
  // preload half0 of kt0 (gu 0..3)
  bf16x8 p0 = *(const bf16x8*)&bw[0*512];
  bf16x8 p1 = *(const bf16x8*)&bw[1*512];
  bf16x8 p2 = *(const bf16x8*)&bw[2*512];
  bf16x8 p3 = *(const bf16x8*)&bw[3*512];
  const ushort_t* bp = bw;
  #pragma unroll 1
  for (int kt = 0; kt < 9; ++kt){
    // load half1 of this kt (gu 4..7) — consumed after half0's MFMAs
    bf16x8 q0 = *(const bf16x8*)&bp[4*512];
    bf16x8 q1 = *(const bf16x8*)&bp[5*512];
    bf16x8 q2 = *(const bf16x8*)&bp[6*512];
    bf16x8 q3 = *(const bf16x8*)&bp[7*512];
    bf16x8 a0 = *(const bf16x8*)&Aln[(0*9+kt)*512];
    bf16x8 a1 = *(const bf16x8*)&Aln[(1*9+kt)*512];
    bf16x8 a2 = *(const bf16x8*)&Aln[(2*9+kt)*512];
    bf16x8 a3 = *(const bf16x8*)&Aln[(3*9+kt)*512];
    // MFMA half0 (gu 0..3) on the preloaded group
    acc[0][0] = __builtin_amdgcn_mfma_f32_16x16x32_bf16(a0, p0, acc[0][0], 0, 0, 0);
    acc[1][0] = __builtin_amdgcn_mfma_f32_16x16x32_bf16(a1, p0, acc[1][0], 0, 0, 0);
    acc[2][0] = __builtin_amdgcn_mfma_f32_16x16x32_bf16(a2, p0, acc[2][0], 0, 0, 0);
    acc[3][0] = __builtin_amdgcn_mfma_f32_16x16x32_bf16(a3, p0, acc[3][0], 0, 0, 0);
    acc[0][1] = __builtin_amdgcn_mfma_f32_16x16x32_bf16(a0, p1, acc[0][1], 0, 0, 0);
    acc[1][1] = __builtin_amdgcn_mfma_f32_16x16x32_bf16(a1, p1, acc[1][1], 0, 0, 0);
    acc[2][1] = __builtin_amdgcn_mfma_f32_16x16x32_bf16(a2, p1, acc[2][1], 0, 0, 0);
    acc[3][1] = __builtin_amdgcn_mfma_f32_16x16x32_bf16(a3, p1, acc[3][1], 0, 0, 0);
    acc[0][2] = __builtin_amdgcn_mfma_f32_16x16x32_bf16(a0, p2, acc[0][2], 0, 0, 0);
    acc[1][2] = __builtin_amdgcn_mfma_f32_16x16x32_bf16(a1, p2, acc[1][2], 0, 0, 0);
    acc[2][2] = __builtin_amdgcn_mfma_f32_16x16x32_bf16(a2, p2, acc[2][2], 0, 0, 0);
    acc[3][2] = __builtin_amdgcn_mfma_f32_16x16x32_bf16(a3, p2, acc[3][2], 0, 0, 0);
    acc[0][3] = __builtin_amdgcn_mfma_f32_16x16x32_bf16(a0, p3, acc[0][3], 0, 0, 0);
    acc[1][3] = __builtin_amdgcn_mfma_f32_16x16x32_bf16(a1, p3, acc[1][3], 0, 0, 0);
    acc[2][3] = __builtin_amdgcn_mfma_f32_16x16x32_bf16(a2, p3, acc[2][3], 0, 0, 0);
    acc[3][3] = __builtin_amdgcn_mfma_f32_16x16x32_bf16(a3, p3, acc[3][3], 0, 0, 0);
    // prefetch half0 of next kt (hidden under half1's MFMAs)
    if (kt < 8){
      p0 = *(const bf16x8*)&bp[4096 + 0*512];
      p1 = *(const bf16x8*)&bp[4096 + 1*512];
      p2 = *(const bf16x8*)&bp[4096 + 2*512];
      p3 = *(const bf16x8*)&bp[4096 + 3*512];
    }
    // MFMA half1 (gu 4..7)
    acc[0][4] = __builtin_amdgcn_mfma_f32_16x16x32_bf16(a0, q0, acc[0][4], 0, 0, 0);
    acc[1][4] = __builtin_amdgcn_mfma_f32_16x16x32_bf16(a1, q0, acc[1][4], 0, 0, 0);
    acc[2][4] = __builtin_amdgcn_mfma_f32_16x16x32_bf16(a2, q0, acc[2][4], 0, 0, 0);
    acc[3][4] = __builtin_amdgcn_mfma_f32_16x16x32_bf16(a3, q0, acc[3][4], 0, 0, 0);
    acc[0][5] = __builtin_amdgcn_mfma_f32_16x16x32_bf16(a0, q1, acc[0][5], 0, 0, 0);
    acc[1][5] = __builtin_amdgcn_mfma_f32_16x16x32_bf16(a1, q1, acc[1][5], 0, 0, 0);
    acc[2][5] = __builtin_amdgcn_mfma_f32_16x16x32_bf16(a2, q1, acc[2][5], 0, 0, 0);
    acc[3][5] = __builtin_amdgcn_mfma_f32_16x16x32_bf16(a3, q1, acc[3][5], 0, 0, 0);
    acc[0][6] = __builtin_amdgcn_mfma_f32_16x16x32_bf16(a0, q2, acc[0][6], 0, 0, 0);
    acc[1][6] = __builtin_amdgcn_mfma_f32_16x16x32_bf16(a1, q2, acc[1][6], 0, 0, 0);
    acc[2][6] = __builtin_amdgcn_mfma_f32_16x16x32_bf16(a2, q2, acc[2][6], 0, 0, 0);
    acc[3][6] = __builtin_amdgcn_mfma_f32_16x16x32_bf16(a3, q2, acc[3][6], 0, 0, 0);
    acc[0][7] = __builtin_amdgcn_mfma_f32_16x16x32_bf16(a0, q3, acc[0][7], 0, 0, 0);
    acc[1][7] = __builtin_amdgcn_mfma_f32_16x16x32_bf16(a1, q3, acc[1][7], 0, 0, 0);
    acc[2][7] = __builtin_amdgcn_mfma_f32_16x16x32_bf16(a2, q3, acc[2][7], 0, 0, 0);
    acc[3][7] = __builtin_amdgcn_mfma_f32_16x16x32_bf16(a3, q3, acc[3][7], 0, 0, 0);
    bp += 4096;
  }
}

// gate nonlinearity + h writeback into A-frag layout; acc idx: i->u, f->2+u, g->4+u, o->6+u
__device__ __forceinline__ void gates_wb(f32x4 (&acc)[4][8], float (&cw)[4][2][4],
                                         ushort_t* __restrict__ Ap, int wbBase){
  #pragma unroll
  for (int mt = 0; mt < 4; ++mt)
    #pragma unroll
    for (int u = 0; u < 2; ++u)
      #pragma unroll
      for (int r = 0; r < 4; ++r){
        float cn = sigmf_(acc[mt][2+u][r])*cw[mt][u][r]
                 + sigmf_(acc[mt][u][r])*tanhf_(acc[mt][4+u][r]);
        float hn = sigmf_(acc[mt][6+u][r])*tanhf_(cn);
        cw[mt][u][r] = cn;
        Ap[mt*4608 + u*256 + r*8 + wbBase] = f2bf(hn);
      }
}

// ---------------- main kernel: 256 blocks x 64 rows, 512 threads (8 waves) ----------------
// Wave w owns h-cols [w*32, w*32+32) of all 4 gates, all 4 m-tiles (acc 128 AGPR).
// Merged-pair schedule: each barrier region runs one LSTM's GEMM alongside the other
// LSTM's gate-VALU + writeback.
__global__ __launch_bounds__(512, 2) void pvlstm_main(
    const ushort_t* __restrict__ ws,
    const ushort_t* __restrict__ speed,
    const ushort_t* __restrict__ pos,
    void* __restrict__ outv)
{
  __shared__ ushort_t ApS[4*9*512];   // A-pack speed-enc / speed-dec (36 KB)
  __shared__ ushort_t ApP[4*9*512];   // A-pack pos-enc / cross-dec   (36 KB)
  __shared__ ushort_t xsS[64*64];     // staged speed inputs (8 KB)
  __shared__ ushort_t xsP[64*64];     // staged pos inputs   (8 KB)
  __shared__ float    ostS[64*64];    // speed outputs stage (16 KB)
  __shared__ float    ostC[64*32];    // crossing outputs stage (8 KB)

  const int f32   = *(const int*)(ws + FLAG_OFS);
  const int tid   = threadIdx.x;
  const int lane  = tid & 63;
  const int w     = tid >> 6;   // 0..7
  const int col16 = lane & 15;
  const int quad  = lane >> 4;
  const int brow0 = blockIdx.x * 64;
  const int wbBase = w*512 + (col16>>3)*128 + quad*32 + (col16&7);

  ushort_t* outu = (ushort_t*)outv;
  float*    outf = (float*)outv;

  const ushort_t* headsp = ws + 4*PACK_W_ELEMS;
  const ushort_t* headcr = headsp + HEAD_ELEMS;
  const ushort_t* aS  = ApS + lane*8;
  const ushort_t* aP  = ApP + lane*8;
  const ushort_t* bwS  = ws + 0*PACK_W_ELEMS + (size_t)w*36864 + (size_t)lane*8;
  const ushort_t* bwP  = ws + 1*PACK_W_ELEMS + (size_t)w*36864 + (size_t)lane*8;
  const ushort_t* bwDS = ws + 2*PACK_W_ELEMS + (size_t)w*36864 + (size_t)lane*8;
  const ushort_t* bwDC = ws + 3*PACK_W_ELEMS + (size_t)w*36864 + (size_t)lane*8;

  float cwA[4][2][4], cwB[4][2][4];
  f32x4 acc[4][8];

  // ---- prologue: stage inputs, zero A-packs, bias column, x_sp(0) ----
  for (int i = tid; i < 4096; i += 512){
    int gi = (brow0 + (i>>6))*64 + (i&63);
    xsS[i] = f2bf(ldin(speed, gi, f32));
    xsP[i] = f2bf(ldin(pos,   gi, f32));
  }
  for (int i = tid; i < 4*9*512/2; i += 512){
    ((unsigned*)ApS)[i] = 0u; ((unsigned*)ApP)[i] = 0u;
  }
  #pragma unroll
  for (int mt = 0; mt < 4; ++mt)
    #pragma unroll
    for (int u = 0; u < 2; ++u)
      #pragma unroll
      for (int r = 0; r < 4; ++r){ cwA[mt][u][r] = 0.f; cwB[mt][u][r] = 0.f; }
  __syncthreads();
  if (tid < 64){
    ushort_t* xpS = &ApS[((tid>>4)*9 + 8)*512 + (tid&15)*8];
    ushort_t* xpP = &ApP[((tid>>4)*9 + 8)*512 + (tid&15)*8];
    *(uint2*)xpS = *(const uint2*)&xsS[tid*64];    // x_sp(0)
    xpS[4] = (ushort_t)0x3f80;                     // bias 1.0 column
    xpP[4] = (ushort_t)0x3f80;
  }
  __syncthreads();

  // ================= encoders: sp (A) and po (B), interleaved =================
  for (int t = 0; t < 16; ++t){
    // R1: gates_po(t-1)+wb -> ApP ; x_po(t) -> ApP.kt8 ; GEMM_sp(t) from ApS
    if (t > 0) gates_wb(acc, cwB, ApP, wbBase);
    if (tid < 64)
      *(uint2*)&ApP[((tid>>4)*9 + 8)*512 + (tid&15)*8] = *(const uint2*)&xsP[tid*64 + t*4];
    gate_gemm(aS, bwS, acc, lane);
    __syncthreads();
    // R2: gates_sp(t)+wb -> ApS ; x_sp(t+1) -> ApS.kt8 ; GEMM_po(t) from ApP
    gates_wb(acc, cwA, ApS, wbBase);
    if (t < 15 && tid < 64)
      *(uint2*)&ApS[((tid>>4)*9 + 8)*512 + (tid&15)*8] = *(const uint2*)&xsS[tid*64 + t*4 + 4];
    gate_gemm(aP, bwP, acc, lane);
    __syncthreads();
  }
  // ---- encoder epilogue: gates_po(15); h0 = h_sp+h_po into BOTH packs; c0 in regs ----
  #pragma unroll
  for (int mt = 0; mt < 4; ++mt)
    #pragma unroll
    for (int u = 0; u < 2; ++u)
      #pragma unroll
      for (int r = 0; r < 4; ++r){
        float cn = sigmf_(acc[mt][2+u][r])*cwB[mt][u][r]
                 + sigmf_(acc[mt][u][r])*tanhf_(acc[mt][4+u][r]);
        float hn = sigmf_(acc[mt][6+u][r])*tanhf_(cn);
        float c0 = cwA[mt][u][r] + cn;
        cwA[mt][u][r] = c0; cwB[mt][u][r] = c0;
        const int ad = mt*4608 + u*256 + r*8 + wbBase;
        ushort_t h0 = f2bf(bf2f(ApS[ad]) + hn);    // own value written in R2(15)
        ApS[ad] = h0; ApP[ad] = h0;
      }
  if (tid < 64){
    *(uint2*)&ApS[((tid>>4)*9 + 8)*512 + (tid&15)*8] = *(const uint2*)&xsS[tid*64 + 60];  // x0 sp
    *(uint2*)&ApP[((tid>>4)*9 + 8)*512 + (tid&15)*8] = *(const uint2*)&xsP[tid*64 + 60];  // x0 po
  }
  __syncthreads();

  // ================= decoders: dsp (A, ApS) and dcr (B, ApP), interleaved =================
  for (int t = 0; t < 16; ++t){
    // R1: head_cr(t-1) [waves 4..7] -> ostC + x_cr(t) ; GEMM_dsp(t) from ApS
    if (t > 0 && w >= 4){
      const int mt = w - 4;
      f32x4 hacc = (f32x4){0.f,0.f,0.f,0.f};
      #pragma unroll
      for (int kt = 0; kt < 9; ++kt){
        bf16x8 a  = *(const bf16x8*)&aP[(mt*9+kt)*512];
        bf16x8 bv = *(const bf16x8*)&headcr[((size_t)kt*64 + lane)*8];
        hacc = __builtin_amdgcn_mfma_f32_16x16x32_bf16(a, bv, hacc, 0, 0, 0);
      }
      const int s = col16;
      #pragma unroll
      for (int r = 0; r < 4; ++r){
        float v = fmaxf(hacc[r], 0.f);             // relu
        const float o = __shfl_xor(v, 1, 64);      // pair logits (lanes 4<->5)
        const int m = mt*16 + quad*4 + r;
        if (s < 4){
          ApP[(mt*9+8)*512 + (m&15)*8 + s] = f2bf(v);          // x_cr(t) feedback
        } else if (s < 6){
          const float mx = fmaxf(v, o);
          const float e0 = __expf(v-mx), e1 = __expf(o-mx);
          ostC[m*32 + (t-1)*2 + (s-4)] = e0*rcp_(e0+e1);       // softmax2 at t-1
        }
      }
    }
    gate_gemm(aS, bwDS, acc, lane);
    __syncthreads();
    // R2: gates_dsp(t)+wb -> ApS ; GEMM_dcr(t) from ApP
    gates_wb(acc, cwA, ApS, wbBase);
    gate_gemm(aP, bwDC, acc, lane);
    __syncthreads();
    // R3: gates_dcr(t)+wb -> ApP ; head_sp(t) [waves 0..3] -> ostS + x_sp(t+1)
    gates_wb(acc, cwB, ApP, wbBase);
    if (w < 4){
      const int mt = w;
      f32x4 hacc = (f32x4){0.f,0.f,0.f,0.f};
      #pragma unroll
      for (int kt = 0; kt < 9; ++kt){
        bf16x8 a  = *(const bf16x8*)&aS[(mt*9+kt)*512];
        bf16x8 bv = *(const bf16x8*)&headsp[((size_t)kt*64 + lane)*8];
        hacc = __builtin_amdgcn_mfma_f32_16x16x32_bf16(a, bv, hacc, 0, 0, 0);
      }
      const int s = col16;
      if (s < 4){
        #pragma unroll
        for (int r = 0; r < 4; ++r){
          float v = fminf(fmaxf(hacc[r], -100.f), 100.f);      // hardtanh(+-100)
          const int m = mt*16 + quad*4 + r;
          ostS[m*64 + t*4 + s] = v;
          ApS[(mt*9+8)*512 + (m&15)*8 + s] = f2bf(v);          // x_sp(t+1) feedback
        }
      }
    }
    __syncthreads();
  }
  // ---- decoder epilogue: head_cr(15) ----
  if (w >= 4){
    const int mt = w - 4;
    f32x4 hacc = (f32x4){0.f,0.f,0.f,0.f};
    #pragma unroll
    for (int kt = 0; kt < 9; ++kt){
      bf16x8 a  = *(const bf16x8*)&aP[(mt*9+kt)*512];
      bf16x8 bv = *(const bf16x8*)&headcr[((size_t)kt*64 + lane)*8];
      hacc = __builtin_amdgcn_mfma_f32_16x16x32_bf16(a, bv, hacc, 0, 0, 0);
    }
    const int s = col16;
    if (s >= 4 && s < 6){
      #pragma unroll
      for (int r = 0; r < 4; ++r){
        float v = fmaxf(hacc[r], 0.f);
        const float o = __shfl_xor(v, 1, 64);
        const int m = mt*16 + quad*4 + r;
        const float mx = fmaxf(v, o);
        const float e0 = __expf(v-mx), e1 = __expf(o-mx);
        ostC[m*32 + 15*2 + (s-4)] = e0*rcp_(e0+e1);
      }
    }
  }
  __syncthreads();

  // ---- coalesced output flush ----
  for (int i = tid; i < 4096; i += 512){
    const int oi = (brow0 + (i>>6))*64 + (i&63);
    const float v = ostS[i];
    if (f32) outf[oi] = v; else outu[oi] = f2bf(v);
  }
  for (int i = tid; i < 2048; i += 512){
    const int oi = 1048576 + (brow0 + (i>>5))*32 + (i&31);
    const float v = ostC[i];
    if (f32) outf[oi] = v; else outu[oi] = f2bf(v);
  }
}

extern "C" void kernel_launch(void* const* d_in, const int* in_sizes, int n_in,
                              void* d_out, int out_size, void* d_ws, size_t ws_size,
                              hipStream_t stream) {
  PackArgs pa;
  pa.wih[0]=(const ushort_t*)d_in[2];  pa.whh[0]=(const ushort_t*)d_in[3];
  pa.bih[0]=(const ushort_t*)d_in[4];  pa.bhh[0]=(const ushort_t*)d_in[5];
  pa.wih[1]=(const ushort_t*)d_in[6];  pa.whh[1]=(const ushort_t*)d_in[7];
  pa.bih[1]=(const ushort_t*)d_in[8];  pa.bhh[1]=(const ushort_t*)d_in[9];
  pa.wih[2]=(const ushort_t*)d_in[10]; pa.whh[2]=(const ushort_t*)d_in[11];
  pa.bih[2]=(const ushort_t*)d_in[12]; pa.bhh[2]=(const ushort_t*)d_in[13];
  pa.wih[3]=(const ushort_t*)d_in[14]; pa.whh[3]=(const ushort_t*)d_in[15];
  pa.bih[3]=(const ushort_t*)d_in[16]; pa.bhh[3]=(const ushort_t*)d_in[17];
  pa.fcsp_w=(const ushort_t*)d_in[18]; pa.fcsp_b=(const ushort_t*)d_in[19];
  pa.fccr_w=(const ushort_t*)d_in[20]; pa.fccr_b=(const ushort_t*)d_in[21];
  pa.emb_w =(const ushort_t*)d_in[22]; pa.emb_b =(const ushort_t*)d_in[23];
  pa.ws = (ushort_t*)d_ws;

  hipLaunchKernelGGL(pack_kernel, dim3((PACK_TOTAL + 255)/256), dim3(256), 0, stream, pa);
  hipLaunchKernelGGL(pvlstm_main, dim3(256), dim3(512), 0, stream,
      (const ushort_t*)d_ws,
      (const ushort_t*)d_in[0], (const ushort_t*)d_in[1],
      d_out);
}